// Round 1
// baseline (3899.431 us; speedup 1.0000x reference)
//
#include <hip/hip_runtime.h>
#include <math.h>

constexpr int NTOK  = 4096;   // H*W
constexpr int CDIM  = 256;
constexpr int NHEAD = 8;
constexpr int HDIM  = 32;
constexpr int MLPD  = 1024;
constexpr float EPS_LN = 1e-5f;
#define QB 4

// ---------------- bilinear 16x downsample (1024->64, align_corners=False) --------
// src coord = 16*i + 7.5 -> average of pixels (16i+7, 16i+8)
__global__ void k_down(const float* __restrict__ x, float* __restrict__ xd) {
    int t = blockIdx.x * 256 + threadIdx.x;      // 0..4095
    int i = t >> 6, j = t & 63;
    int r0 = 16 * i + 7, c0 = 16 * j + 7;
    float v = x[r0 * 1024 + c0] + x[r0 * 1024 + c0 + 1] +
              x[(r0 + 1) * 1024 + c0] + x[(r0 + 1) * 1024 + c0 + 1];
    xd[t] = 0.25f * v;
}

// ---------------- conv3x3 (1 -> 256 channels), zero pad, ReLU --------------------
__global__ void k_pe3(const float* __restrict__ xd, const float* __restrict__ w,
                      const float* __restrict__ b, float* __restrict__ y) {
    int o = blockIdx.y;
    int t = blockIdx.x * 256 + threadIdx.x;  // spatial pos
    int yy = t >> 6, xx = t & 63;
    float acc = b[o];
#pragma unroll
    for (int ky = 0; ky < 3; ++ky) {
        int sy = yy + ky - 1;
        if (sy < 0 || sy > 63) continue;
#pragma unroll
        for (int kx = 0; kx < 3; ++kx) {
            int sx = xx + kx - 1;
            if (sx < 0 || sx > 63) continue;
            acc += w[o * 9 + ky * 3 + kx] * xd[sy * 64 + sx];
        }
    }
    y[o * NTOK + t] = fmaxf(acc, 0.0f);
}

// ---------------- LayerNorm over channels (per spatial position) -----------------
// block = 256 threads (one per channel), grid = 4096 (one per position)
// optional: += pos[c] + pe[c][n]
__global__ __launch_bounds__(256) void k_ln(const float* __restrict__ x,
                                            const float* __restrict__ g,
                                            const float* __restrict__ bvec,
                                            const float* __restrict__ pe,
                                            const float* __restrict__ pos,
                                            float* __restrict__ y) {
    int n = blockIdx.x;
    int c = threadIdx.x;
    float v = x[c * NTOK + n];
    float sm = v;
#pragma unroll
    for (int off = 32; off > 0; off >>= 1) sm += __shfl_xor(sm, off, 64);
    __shared__ float ra[4], rb[4];
    int wid = threadIdx.x >> 6;
    if ((threadIdx.x & 63) == 0) ra[wid] = sm;
    __syncthreads();
    float mu = (ra[0] + ra[1] + ra[2] + ra[3]) * (1.0f / CDIM);
    float d = v - mu;
    float sq = d * d;
#pragma unroll
    for (int off = 32; off > 0; off >>= 1) sq += __shfl_xor(sq, off, 64);
    if ((threadIdx.x & 63) == 0) rb[wid] = sq;
    __syncthreads();
    float var = (rb[0] + rb[1] + rb[2] + rb[3]) * (1.0f / CDIM);
    float rs = rsqrtf(var + EPS_LN);
    float outv = d * rs * g[c] + bvec[c];
    if (pe) outv += pos[c] + pe[c * NTOK + n];
    y[c * NTOK + n] = outv;
}

// ---------------- generic f32 GEMM: Y[M][4096] = W[M][K] * X[K][4096] ------------
// + bias[m], optional exact-GELU, optional residual add. 64x64 tile, 4x4 micro.
__device__ __forceinline__ float gelu_exact(float x) {
    return 0.5f * x * (1.0f + erff(x * 0.70710678118654752f));
}

__global__ __launch_bounds__(256) void k_mm(const float* __restrict__ W,
                                            const float* __restrict__ X,
                                            const float* __restrict__ bias,
                                            const float* __restrict__ res,
                                            float* __restrict__ Y,
                                            int M, int K, int act) {
    __shared__ float Ws[16][68];  // [k][m], padded (272B rows: 16B aligned, no 4-way conflicts)
    __shared__ float Xs[16][68];  // [k][n]
    int tid = threadIdx.x;
    int tx = tid & 15, ty = tid >> 4;
    int nBase = blockIdx.x * 64, mBase = blockIdx.y * 64;
    float acc[4][4] = {{0.f}};
    for (int k0 = 0; k0 < K; k0 += 16) {
        {
            int kk = tid & 15;
            int m0 = tid >> 4;
#pragma unroll
            for (int i = 0; i < 4; ++i) {
                int m = m0 + 16 * i;
                Ws[kk][m] = W[(mBase + m) * K + k0 + kk];
            }
            int r = tid >> 6;
            int c = tid & 63;
#pragma unroll
            for (int i = 0; i < 4; ++i)
                Xs[r + 4 * i][c] = X[(k0 + r + 4 * i) * NTOK + nBase + c];
        }
        __syncthreads();
#pragma unroll
        for (int kk = 0; kk < 16; ++kk) {
            const float4 wv = *(const float4*)&Ws[kk][ty * 4];
            const float4 xv = *(const float4*)&Xs[kk][tx * 4];
            float wr[4] = {wv.x, wv.y, wv.z, wv.w};
            float xr[4] = {xv.x, xv.y, xv.z, xv.w};
#pragma unroll
            for (int a = 0; a < 4; ++a)
#pragma unroll
                for (int b2 = 0; b2 < 4; ++b2) acc[a][b2] += wr[a] * xr[b2];
        }
        __syncthreads();
    }
#pragma unroll
    for (int a = 0; a < 4; ++a) {
        int m = mBase + ty * 4 + a;
        float e[4];
#pragma unroll
        for (int b2 = 0; b2 < 4; ++b2) e[b2] = acc[a][b2] + bias[m];
        if (act == 1) {
#pragma unroll
            for (int b2 = 0; b2 < 4; ++b2) e[b2] = gelu_exact(e[b2]);
        }
        float* dst = Y + (size_t)m * NTOK + nBase + tx * 4;
        if (res) {
            const float4 rv = *(const float4*)(res + (size_t)m * NTOK + nBase + tx * 4);
            e[0] += rv.x; e[1] += rv.y; e[2] += rv.z; e[3] += rv.w;
        }
        float4 o4 = {e[0], e[1], e[2], e[3]};
        *(float4*)dst = o4;
    }
}

// ---------------- attention: scores=q^T k / scale, softmax, PV -------------------
// grid (NTOK/QB, NHEAD), block 256. Thread owns keys m = 4*tid + 1024*j + e.
__global__ __launch_bounds__(256, 2) void k_attn(const float* __restrict__ q,
                                                 const float* __restrict__ kmat,
                                                 const float* __restrict__ vmat,
                                                 const float* __restrict__ scl,
                                                 float* __restrict__ out) {
    int h = blockIdx.y;
    int n0 = blockIdx.x * QB;
    int tid = threadIdx.x;
    __shared__ float qs[QB][HDIM];
    __shared__ float redw[4][QB];
    __shared__ float rbuf[HDIM][257];
    __shared__ float pbuf[HDIM][9];

    float invs = 1.0f / scl[0];
    if (tid < QB * HDIM) {
        int qi = tid / HDIM, d = tid % HDIM;
        qs[qi][d] = q[(h * HDIM + d) * NTOK + n0 + qi] * invs;
    }
    __syncthreads();

    // ---- phase A: scores in registers ----
    float s[QB][16];
#pragma unroll
    for (int qi = 0; qi < QB; ++qi)
#pragma unroll
        for (int e = 0; e < 16; ++e) s[qi][e] = 0.f;

    const float* kh = kmat + (size_t)h * HDIM * NTOK;
    for (int d = 0; d < HDIM; ++d) {
        float qd[QB];
#pragma unroll
        for (int qi = 0; qi < QB; ++qi) qd[qi] = qs[qi][d];
        const float* kr = kh + d * NTOK + 4 * tid;
#pragma unroll
        for (int j = 0; j < 4; ++j) {
            const float4 kv4 = *(const float4*)(kr + 1024 * j);
            float ke[4] = {kv4.x, kv4.y, kv4.z, kv4.w};
#pragma unroll
            for (int qi = 0; qi < QB; ++qi)
#pragma unroll
                for (int e = 0; e < 4; ++e) s[qi][4 * j + e] += qd[qi] * ke[e];
        }
    }

    // ---- block max per query ----
    float mx[QB];
#pragma unroll
    for (int qi = 0; qi < QB; ++qi) {
        float m = -1e30f;
#pragma unroll
        for (int e = 0; e < 16; ++e) m = fmaxf(m, s[qi][e]);
#pragma unroll
        for (int off = 32; off > 0; off >>= 1) m = fmaxf(m, __shfl_xor(m, off, 64));
        mx[qi] = m;
    }
    int wid = tid >> 6;
    if ((tid & 63) == 0) {
#pragma unroll
        for (int qi = 0; qi < QB; ++qi) redw[wid][qi] = mx[qi];
    }
    __syncthreads();
#pragma unroll
    for (int qi = 0; qi < QB; ++qi)
        mx[qi] = fmaxf(fmaxf(redw[0][qi], redw[1][qi]), fmaxf(redw[2][qi], redw[3][qi]));
    __syncthreads();

    // ---- exp + block sum ----
    float inv_l[QB];
#pragma unroll
    for (int qi = 0; qi < QB; ++qi) {
        float sum = 0.f;
#pragma unroll
        for (int e = 0; e < 16; ++e) {
            float p = __expf(s[qi][e] - mx[qi]);
            s[qi][e] = p;
            sum += p;
        }
#pragma unroll
        for (int off = 32; off > 0; off >>= 1) sum += __shfl_xor(sum, off, 64);
        inv_l[qi] = sum;  // wave sum, finish below
    }
    if ((tid & 63) == 0) {
#pragma unroll
        for (int qi = 0; qi < QB; ++qi) redw[wid][qi] = inv_l[qi];
    }
    __syncthreads();
#pragma unroll
    for (int qi = 0; qi < QB; ++qi)
        inv_l[qi] = 1.0f / (redw[0][qi] + redw[1][qi] + redw[2][qi] + redw[3][qi]);

    // ---- phase C: PV, per-thread partial accumulators ----
    float acc[QB][HDIM];
    const float* vh = vmat + (size_t)h * HDIM * NTOK;
#pragma unroll
    for (int d = 0; d < HDIM; ++d) {
        const float* vr = vh + d * NTOK + 4 * tid;
        float a[QB] = {0.f, 0.f, 0.f, 0.f};
#pragma unroll
        for (int j = 0; j < 4; ++j) {
            const float4 vv4 = *(const float4*)(vr + 1024 * j);
            float ve[4] = {vv4.x, vv4.y, vv4.z, vv4.w};
#pragma unroll
            for (int qi = 0; qi < QB; ++qi)
#pragma unroll
                for (int e = 0; e < 4; ++e) a[qi] += s[qi][4 * j + e] * ve[e];
        }
#pragma unroll
        for (int qi = 0; qi < QB; ++qi) acc[qi][d] = a[qi];
    }

    // ---- cross-thread reduction via LDS transpose, one query at a time ----
#pragma unroll
    for (int qi = 0; qi < QB; ++qi) {
        __syncthreads();
#pragma unroll
        for (int d = 0; d < HDIM; ++d) rbuf[d][tid] = acc[qi][d];
        __syncthreads();
        int dd = tid & 31, seg = tid >> 5;   // seg 0..7
        float part = 0.f;
#pragma unroll
        for (int i = 0; i < 32; ++i) part += rbuf[dd][(seg << 5) + i];
        pbuf[dd][seg] = part;
        __syncthreads();
        if (tid < HDIM) {
            float tot = 0.f;
#pragma unroll
            for (int i = 0; i < 8; ++i) tot += pbuf[tid][i];
            out[(h * HDIM + tid) * NTOK + n0 + qi] = tot * inv_l[qi];
        }
    }
}

// ------------------------------------------------------------------------------
extern "C" void kernel_launch(void* const* d_in, const int* in_sizes, int n_in,
                              void* d_out, int out_size, void* d_ws, size_t ws_size,
                              hipStream_t stream) {
    const float* rgb    = (const float*)d_in[0];
    const float* dpt    = (const float*)d_in[1];
    const float* x_dpt  = (const float*)d_in[2];
    const float* wq     = (const float*)d_in[3];
    const float* bq     = (const float*)d_in[4];
    const float* wk     = (const float*)d_in[5];
    const float* bk     = (const float*)d_in[6];
    const float* wv     = (const float*)d_in[7];
    const float* bv     = (const float*)d_in[8];
    const float* wo     = (const float*)d_in[9];
    const float* bo     = (const float*)d_in[10];
    const float* g_rgb  = (const float*)d_in[11];
    const float* b_rgb  = (const float*)d_in[12];
    const float* g_dpt  = (const float*)d_in[13];
    const float* b_dpt  = (const float*)d_in[14];
    const float* g1     = (const float*)d_in[15];
    const float* b1     = (const float*)d_in[16];
    const float* g2     = (const float*)d_in[17];
    const float* b2     = (const float*)d_in[18];
    const float* w_mlp1 = (const float*)d_in[19];
    const float* b_mlp1 = (const float*)d_in[20];
    const float* w_mlp2 = (const float*)d_in[21];
    const float* b_mlp2 = (const float*)d_in[22];
    const float* w_de1  = (const float*)d_in[23];
    const float* b_de1  = (const float*)d_in[24];
    const float* w_de2  = (const float*)d_in[25];
    const float* b_de2  = (const float*)d_in[26];
    const float* pos    = (const float*)d_in[27];
    const float* scale  = (const float*)d_in[28];
    float* out = (float*)d_out;

    float* ws = (float*)d_ws;
    const size_t S = (size_t)CDIM * NTOK;   // one [256][4096] slot
    float* s0 = ws + 0 * S;
    float* s1 = ws + 1 * S;
    float* s2 = ws + 2 * S;
    float* s3 = ws + 3 * S;
    float* s4 = ws + 4 * S;
    float* s5 = ws + 5 * S;
    float* xd = ws + 6 * S;                 // 4096 floats

    dim3 mmg256(NTOK / 64, CDIM / 64);      // (64,4)
    dim3 mmg1024(NTOK / 64, MLPD / 64);     // (64,16)

    // depth positional embedding
    k_down<<<16, 256, 0, stream>>>(x_dpt, xd);
    k_pe3<<<dim3(16, 256), 256, 0, stream>>>(xd, w_de1, b_de1, s0);           // pe3 @ s0
    k_mm<<<mmg256, 256, 0, stream>>>(w_de2, s0, b_de2, nullptr, s1, CDIM, CDIM, 0); // pe @ s1

    // layernorms + pos + pe
    k_ln<<<NTOK, 256, 0, stream>>>(rgb, g_rgb, b_rgb, s1, pos, s2);           // a_q  @ s2
    k_ln<<<NTOK, 256, 0, stream>>>(dpt, g_dpt, b_dpt, s1, pos, s3);           // a_kv @ s3

    // qkv projections
    k_mm<<<mmg256, 256, 0, stream>>>(wq, s2, bq, nullptr, s0, CDIM, CDIM, 0); // q @ s0
    k_mm<<<mmg256, 256, 0, stream>>>(wk, s3, bk, nullptr, s4, CDIM, CDIM, 0); // k @ s4
    k_mm<<<mmg256, 256, 0, stream>>>(wv, s3, bv, nullptr, s5, CDIM, CDIM, 0); // v @ s5

    // attention
    k_attn<<<dim3(NTOK / QB, NHEAD), 256, 0, stream>>>(s0, s4, s5, scale, s1); // fused @ s1

    // output projection + residual(rgb)
    k_mm<<<mmg256, 256, 0, stream>>>(wo, s1, bo, rgb, s2, CDIM, CDIM, 0);     // out @ s2
    k_ln<<<NTOK, 256, 0, stream>>>(s2, g1, b1, nullptr, nullptr, s0);         // out_ln @ s0

    // MLP
    k_mm<<<mmg1024, 256, 0, stream>>>(w_mlp1, s0, b_mlp1, nullptr, s1, MLPD, CDIM, 1); // h @ s1..s4 (gelu)
    k_mm<<<mmg256, 256, 0, stream>>>(w_mlp2, s1, b_mlp2, s0, s5, CDIM, MLPD, 0);       // out2 @ s5 (+out_ln)

    // final LN -> d_out
    k_ln<<<NTOK, 256, 0, stream>>>(s5, g2, b2, nullptr, nullptr, out);
}

// Round 2
// 493.129 us; speedup vs baseline: 7.9075x; 7.9075x over previous
//
#include <hip/hip_runtime.h>
#include <math.h>

constexpr int NTOK  = 4096;   // H*W
constexpr int CDIM  = 256;
constexpr int NHEAD = 8;
constexpr int HDIM  = 32;
constexpr int MLPD  = 1024;
constexpr float EPS_LN = 1e-5f;

typedef __attribute__((ext_vector_type(8))) short bf16x8;
typedef __attribute__((ext_vector_type(4))) float floatx4;

__device__ __forceinline__ unsigned short f2bf(float x) {
    union { float f; unsigned u; } v; v.f = x;
    unsigned r = v.u + 0x7fff + ((v.u >> 16) & 1);
    return (unsigned short)(r >> 16);
}

// ---------------- bilinear 16x downsample (1024->64, align_corners=False) --------
__global__ void k_down(const float* __restrict__ x, float* __restrict__ xd) {
    int t = blockIdx.x * 256 + threadIdx.x;
    int i = t >> 6, j = t & 63;
    int r0 = 16 * i + 7, c0 = 16 * j + 7;
    float v = x[r0 * 1024 + c0] + x[r0 * 1024 + c0 + 1] +
              x[(r0 + 1) * 1024 + c0] + x[(r0 + 1) * 1024 + c0 + 1];
    xd[t] = 0.25f * v;
}

// ---------------- conv3x3 (1 -> 256 channels), zero pad, ReLU --------------------
__global__ void k_pe3(const float* __restrict__ xd, const float* __restrict__ w,
                      const float* __restrict__ b, float* __restrict__ y) {
    int o = blockIdx.y;
    int t = blockIdx.x * 256 + threadIdx.x;
    int yy = t >> 6, xx = t & 63;
    float acc = b[o];
#pragma unroll
    for (int ky = 0; ky < 3; ++ky) {
        int sy = yy + ky - 1;
        if (sy < 0 || sy > 63) continue;
#pragma unroll
        for (int kx = 0; kx < 3; ++kx) {
            int sx = xx + kx - 1;
            if (sx < 0 || sx > 63) continue;
            acc += w[o * 9 + ky * 3 + kx] * xd[sy * 64 + sx];
        }
    }
    y[o * NTOK + t] = fmaxf(acc, 0.0f);
}

// ---------------- LayerNorm over channels (per spatial position) -----------------
__global__ __launch_bounds__(256) void k_ln(const float* __restrict__ x,
                                            const float* __restrict__ g,
                                            const float* __restrict__ bvec,
                                            const float* __restrict__ pe,
                                            const float* __restrict__ pos,
                                            float* __restrict__ y) {
    int n = blockIdx.x;
    int c = threadIdx.x;
    float v = x[c * NTOK + n];
    float sm = v;
#pragma unroll
    for (int off = 32; off > 0; off >>= 1) sm += __shfl_xor(sm, off, 64);
    __shared__ float ra[4], rb[4];
    int wid = threadIdx.x >> 6;
    if ((threadIdx.x & 63) == 0) ra[wid] = sm;
    __syncthreads();
    float mu = (ra[0] + ra[1] + ra[2] + ra[3]) * (1.0f / CDIM);
    float d = v - mu;
    float sq = d * d;
#pragma unroll
    for (int off = 32; off > 0; off >>= 1) sq += __shfl_xor(sq, off, 64);
    if ((threadIdx.x & 63) == 0) rb[wid] = sq;
    __syncthreads();
    float var = (rb[0] + rb[1] + rb[2] + rb[3]) * (1.0f / CDIM);
    float rs = rsqrtf(var + EPS_LN);
    float outv = d * rs * g[c] + bvec[c];
    if (pe) outv += pos[c] + pe[c * NTOK + n];
    y[c * NTOK + n] = outv;
}

// ---------------- generic f32 GEMM: Y[M][4096] = W[M][K] * X[K][4096] ------------
// mode 0: f32 out (+bias, optional gelu/residual)
// mode 1: bf16 out transposed [h][n][d], scaled by 1/scl[0] if scl != null
// mode 2: bf16 out natural [c][n]
__device__ __forceinline__ float gelu_exact(float x) {
    return 0.5f * x * (1.0f + erff(x * 0.70710678118654752f));
}

__global__ __launch_bounds__(256) void k_mm(const float* __restrict__ W,
                                            const float* __restrict__ X,
                                            const float* __restrict__ bias,
                                            const float* __restrict__ res,
                                            float* __restrict__ Y,
                                            unsigned short* __restrict__ Yb,
                                            int M, int K, int act, int mode,
                                            const float* __restrict__ scl) {
    __shared__ float Ws[16][68];
    __shared__ float Xs[16][68];
    int tid = threadIdx.x;
    int tx = tid & 15, ty = tid >> 4;
    int nBase = blockIdx.x * 64, mBase = blockIdx.y * 64;
    float acc[4][4] = {{0.f}};
    for (int k0 = 0; k0 < K; k0 += 16) {
        {
            int kk = tid & 15;
            int m0 = tid >> 4;
#pragma unroll
            for (int i = 0; i < 4; ++i) {
                int m = m0 + 16 * i;
                Ws[kk][m] = W[(mBase + m) * K + k0 + kk];
            }
            int r = tid >> 6;
            int c = tid & 63;
#pragma unroll
            for (int i = 0; i < 4; ++i)
                Xs[r + 4 * i][c] = X[(k0 + r + 4 * i) * NTOK + nBase + c];
        }
        __syncthreads();
#pragma unroll
        for (int kk = 0; kk < 16; ++kk) {
            const float4 wv = *(const float4*)&Ws[kk][ty * 4];
            const float4 xv = *(const float4*)&Xs[kk][tx * 4];
            float wr[4] = {wv.x, wv.y, wv.z, wv.w};
            float xr[4] = {xv.x, xv.y, xv.z, xv.w};
#pragma unroll
            for (int a = 0; a < 4; ++a)
#pragma unroll
                for (int b2 = 0; b2 < 4; ++b2) acc[a][b2] += wr[a] * xr[b2];
        }
        __syncthreads();
    }
    float sc = 1.0f;
    if (mode == 1 && scl) sc = 1.0f / scl[0];
#pragma unroll
    for (int a = 0; a < 4; ++a) {
        int m = mBase + ty * 4 + a;
        float e[4];
#pragma unroll
        for (int b2 = 0; b2 < 4; ++b2) e[b2] = acc[a][b2] + bias[m];
        int n0 = nBase + tx * 4;
        if (mode == 1) {
            int h = m >> 5, d = m & 31;
#pragma unroll
            for (int b2 = 0; b2 < 4; ++b2)
                Yb[((size_t)h * NTOK + n0 + b2) * HDIM + d] = f2bf(e[b2] * sc);
        } else if (mode == 2) {
            ushort4 o4;
            o4.x = f2bf(e[0]); o4.y = f2bf(e[1]); o4.z = f2bf(e[2]); o4.w = f2bf(e[3]);
            *(ushort4*)&Yb[(size_t)m * NTOK + n0] = o4;
        } else {
            if (act == 1) {
#pragma unroll
                for (int b2 = 0; b2 < 4; ++b2) e[b2] = gelu_exact(e[b2]);
            }
            if (res) {
                const float4 rv = *(const float4*)(res + (size_t)m * NTOK + n0);
                e[0] += rv.x; e[1] += rv.y; e[2] += rv.z; e[3] += rv.w;
            }
            float4 o4 = {e[0], e[1], e[2], e[3]};
            *(float4*)(Y + (size_t)m * NTOK + n0) = o4;
        }
    }
}

// ---------------- bf16 MFMA flash attention --------------------------------------
// grid (64, 8): block = (64 queries, head). 4 waves x 16 queries.
// qbf, kbf: [h][n][d] bf16 (q pre-scaled by 1/scale). vbf: [c][n] bf16.
// out: fused f32 [c][n].
#define LDK 40   // Qt/Kt row stride (elems): 80 B -> 2-way-only conflicts
#define LDV 72   // Vt/Pt row stride (elems): 144 B -> 2-way-only conflicts

__global__ __launch_bounds__(256, 4) void k_fattn(const unsigned short* __restrict__ qbf,
                                                  const unsigned short* __restrict__ kbf,
                                                  const unsigned short* __restrict__ vbf,
                                                  float* __restrict__ outf) {
    int h = blockIdx.y;
    int q0 = blockIdx.x * 64;
    int tid = threadIdx.x;
    int wid = tid >> 6;
    int lane = tid & 63;
    int lo16 = lane & 15;
    int quad = lane >> 4;

    __shared__ unsigned short Qt[64 * LDK];          // [q][d]
    __shared__ unsigned short Kt[64 * LDK];          // [key][d]
    __shared__ unsigned short Vt[32 * LDV];          // [d][key]
    __shared__ unsigned short Pt[4][16 * LDV];       // per-wave [q][key]

    // load Q tile (4 KB): thread -> row tid>>2, col (tid&3)*8
    {
        int r = tid >> 2, c = (tid & 3) * 8;
        *(int4*)&Qt[r * LDK + c] =
            *(const int4*)(qbf + ((size_t)h * NTOK + q0 + r) * HDIM + c);
    }
    __syncthreads();

    bf16x8 aq = *(const bf16x8*)&Qt[(wid * 16 + lo16) * LDK + quad * 8];

    floatx4 o0 = {0.f, 0.f, 0.f, 0.f};
    floatx4 o1 = {0.f, 0.f, 0.f, 0.f};
    float mrun[4] = {-1e30f, -1e30f, -1e30f, -1e30f};
    float lrun[4] = {0.f, 0.f, 0.f, 0.f};

    for (int kt = 0; kt < NTOK / 64; ++kt) {
        int k0 = kt * 64;
        // stage K,V tile
        int4 kreg = *(const int4*)(kbf + ((size_t)h * NTOK + k0 + (tid >> 2)) * HDIM + (tid & 3) * 8);
        int4 vreg = *(const int4*)(vbf + (size_t)(h * HDIM + (tid >> 3)) * NTOK + k0 + (tid & 7) * 8);
        __syncthreads();   // previous tile's LDS reads done
        *(int4*)&Kt[(tid >> 2) * LDK + (tid & 3) * 8] = kreg;
        *(int4*)&Vt[(tid >> 3) * LDV + (tid & 7) * 8] = vreg;
        __syncthreads();

        // ---- S = Q^T K  (4 MFMAs: 16q x 64k) ----
        floatx4 s[4];
        floatx4 z = {0.f, 0.f, 0.f, 0.f};
#pragma unroll
        for (int c = 0; c < 4; ++c) {
            bf16x8 bk = *(const bf16x8*)&Kt[(c * 16 + lo16) * LDK + quad * 8];
            s[c] = __builtin_amdgcn_mfma_f32_16x16x32_bf16(aq, bk, z, 0, 0, 0);
        }

        // ---- online softmax (row q = quad*4+r, distributed over 16 lanes) ----
        float alpha[4], rowsum[4];
#pragma unroll
        for (int r = 0; r < 4; ++r) {
            float mx = fmaxf(fmaxf(s[0][r], s[1][r]), fmaxf(s[2][r], s[3][r]));
#pragma unroll
            for (int off = 1; off < 16; off <<= 1) mx = fmaxf(mx, __shfl_xor(mx, off, 64));
            float mnew = fmaxf(mrun[r], mx);
            alpha[r] = __expf(mrun[r] - mnew);
            mrun[r] = mnew;
            float rs = 0.f;
#pragma unroll
            for (int c = 0; c < 4; ++c) {
                float p = __expf(s[c][r] - mnew);
                s[c][r] = p;
                rs += p;
            }
            rowsum[r] = rs;
        }
        // write P (bf16) to LDS in A-operand layout source ([q][key])
#pragma unroll
        for (int c = 0; c < 4; ++c)
#pragma unroll
            for (int r = 0; r < 4; ++r)
                Pt[wid][(quad * 4 + r) * LDV + c * 16 + lo16] = f2bf(s[c][r]);
#pragma unroll
        for (int r = 0; r < 4; ++r) {
            float rs = rowsum[r];
#pragma unroll
            for (int off = 1; off < 16; off <<= 1) rs += __shfl_xor(rs, off, 64);
            lrun[r] = lrun[r] * alpha[r] + rs;
        }
        // rescale O
#pragma unroll
        for (int r = 0; r < 4; ++r) { o0[r] *= alpha[r]; o1[r] *= alpha[r]; }
        __syncthreads();   // P visible (and keeps waves together before next stage)

        // ---- O += P V^T  (4 MFMAs: 16q x 32d, k=64 keys) ----
#pragma unroll
        for (int kc = 0; kc < 2; ++kc) {
            bf16x8 ap = *(const bf16x8*)&Pt[wid][lo16 * LDV + kc * 32 + quad * 8];
            bf16x8 bv0 = *(const bf16x8*)&Vt[(0 * 16 + lo16) * LDV + kc * 32 + quad * 8];
            bf16x8 bv1 = *(const bf16x8*)&Vt[(1 * 16 + lo16) * LDV + kc * 32 + quad * 8];
            o0 = __builtin_amdgcn_mfma_f32_16x16x32_bf16(ap, bv0, o0, 0, 0, 0);
            o1 = __builtin_amdgcn_mfma_f32_16x16x32_bf16(ap, bv1, o1, 0, 0, 0);
        }
    }

    // ---- epilogue: O /= l, store f32 [c][n] ----
    int q = q0 + wid * 16 + quad * 4;
#pragma unroll
    for (int r = 0; r < 4; ++r) {
        float inv = 1.0f / lrun[r];
        o0[r] *= inv; o1[r] *= inv;
    }
    float4 w0 = {o0[0], o0[1], o0[2], o0[3]};
    float4 w1 = {o1[0], o1[1], o1[2], o1[3]};
    *(float4*)&outf[(size_t)(h * HDIM + 0 * 16 + lo16) * NTOK + q] = w0;
    *(float4*)&outf[(size_t)(h * HDIM + 1 * 16 + lo16) * NTOK + q] = w1;
}

// ------------------------------------------------------------------------------
extern "C" void kernel_launch(void* const* d_in, const int* in_sizes, int n_in,
                              void* d_out, int out_size, void* d_ws, size_t ws_size,
                              hipStream_t stream) {
    const float* rgb    = (const float*)d_in[0];
    const float* dpt    = (const float*)d_in[1];
    const float* x_dpt  = (const float*)d_in[2];
    const float* wq     = (const float*)d_in[3];
    const float* bq     = (const float*)d_in[4];
    const float* wk     = (const float*)d_in[5];
    const float* bk     = (const float*)d_in[6];
    const float* wv     = (const float*)d_in[7];
    const float* bv     = (const float*)d_in[8];
    const float* wo     = (const float*)d_in[9];
    const float* bo     = (const float*)d_in[10];
    const float* g_rgb  = (const float*)d_in[11];
    const float* b_rgb  = (const float*)d_in[12];
    const float* g_dpt  = (const float*)d_in[13];
    const float* b_dpt  = (const float*)d_in[14];
    const float* g1     = (const float*)d_in[15];
    const float* b1     = (const float*)d_in[16];
    const float* g2     = (const float*)d_in[17];
    const float* b2     = (const float*)d_in[18];
    const float* w_mlp1 = (const float*)d_in[19];
    const float* b_mlp1 = (const float*)d_in[20];
    const float* w_mlp2 = (const float*)d_in[21];
    const float* b_mlp2 = (const float*)d_in[22];
    const float* w_de1  = (const float*)d_in[23];
    const float* b_de1  = (const float*)d_in[24];
    const float* w_de2  = (const float*)d_in[25];
    const float* b_de2  = (const float*)d_in[26];
    const float* pos    = (const float*)d_in[27];
    const float* scale  = (const float*)d_in[28];
    float* out = (float*)d_out;

    float* ws = (float*)d_ws;
    const size_t S = (size_t)CDIM * NTOK;   // one [256][4096] f32 slot
    float* s0 = ws + 0 * S;
    float* s1 = ws + 1 * S;
    float* s2 = ws + 2 * S;
    float* s3 = ws + 3 * S;
    float* s4 = ws + 4 * S;
    float* s5 = ws + 5 * S;
    float* xd = ws + 6 * S;                 // 4096 floats

    // bf16 buffers carved from free slots (each 2 MB = half a slot)
    unsigned short* q_bf = (unsigned short*)s0;                  // [8][4096][32]
    unsigned short* k_bf = (unsigned short*)(s0 + S / 2);        // [8][4096][32]
    unsigned short* v_bf = (unsigned short*)s4;                  // [256][4096]

    dim3 mmg256(NTOK / 64, CDIM / 64);
    dim3 mmg1024(NTOK / 64, MLPD / 64);

    // depth positional embedding (pe3 uses s5 as scratch; s0 is reserved for q/k bf16)
    k_down<<<16, 256, 0, stream>>>(x_dpt, xd);
    k_pe3<<<dim3(16, 256), 256, 0, stream>>>(xd, w_de1, b_de1, s5);
    k_mm<<<mmg256, 256, 0, stream>>>(w_de2, s5, b_de2, nullptr, s1, nullptr, CDIM, CDIM, 0, 0, nullptr); // pe @ s1

    // layernorms + pos + pe
    k_ln<<<NTOK, 256, 0, stream>>>(rgb, g_rgb, b_rgb, s1, pos, s2);   // a_q  @ s2
    k_ln<<<NTOK, 256, 0, stream>>>(dpt, g_dpt, b_dpt, s1, pos, s3);   // a_kv @ s3

    // qkv projections -> bf16 attention layouts
    k_mm<<<mmg256, 256, 0, stream>>>(wq, s2, bq, nullptr, nullptr, q_bf, CDIM, CDIM, 0, 1, scale);
    k_mm<<<mmg256, 256, 0, stream>>>(wk, s3, bk, nullptr, nullptr, k_bf, CDIM, CDIM, 0, 1, nullptr);
    k_mm<<<mmg256, 256, 0, stream>>>(wv, s3, bv, nullptr, nullptr, v_bf, CDIM, CDIM, 0, 2, nullptr);

    // flash attention -> fused f32 @ s1
    k_fattn<<<dim3(NTOK / 64, NHEAD), 256, 0, stream>>>(q_bf, k_bf, v_bf, s1);

    // output projection + residual(rgb)
    k_mm<<<mmg256, 256, 0, stream>>>(wo, s1, bo, rgb, s2, nullptr, CDIM, CDIM, 0, 0, nullptr); // out @ s2
    k_ln<<<NTOK, 256, 0, stream>>>(s2, g1, b1, nullptr, nullptr, s0);                          // out_ln @ s0

    // MLP
    k_mm<<<mmg1024, 256, 0, stream>>>(w_mlp1, s0, b_mlp1, nullptr, s1, nullptr, MLPD, CDIM, 1, 0, nullptr); // h @ s1..s4
    k_mm<<<mmg256, 256, 0, stream>>>(w_mlp2, s1, b_mlp2, s0, s5, nullptr, CDIM, MLPD, 0, 0, nullptr);       // out2 @ s5

    // final LN -> d_out
    k_ln<<<NTOK, 256, 0, stream>>>(s5, g2, b2, nullptr, nullptr, out);
}

// Round 3
// 267.561 us; speedup vs baseline: 14.5740x; 1.8431x over previous
//
#include <hip/hip_runtime.h>
#include <hip/hip_bf16.h>
#include <math.h>

constexpr int NTOK = 4096;
constexpr int CDIM = 256;
constexpr int MLPD = 1024;
constexpr float EPS_LN = 1e-5f;

typedef __attribute__((ext_vector_type(8))) short bf16x8;
typedef __attribute__((ext_vector_type(4))) float floatx4;
typedef unsigned short u16;
typedef unsigned int u32;

__device__ __forceinline__ u16 f2bf(float x) {
    union { float f; u32 u; } v; v.f = x;
    u32 r = v.u + 0x7fff + ((v.u >> 16) & 1);
    return (u16)(r >> 16);
}
__device__ __forceinline__ float bf2f(u16 u) {
    union { u32 i; float f; } v; v.i = ((u32)u) << 16; return v.f;
}
__device__ __forceinline__ u32 pkbf(float a, float b) {
    __hip_bfloat162 h = __float22bfloat162_rn(make_float2(a, b));
    union { __hip_bfloat162 h; u32 u; } v; v.h = h; return v.u;
}
__device__ __forceinline__ float gelu_exact(float x) {
    return 0.5f * x * (1.0f + erff(x * 0.70710678118654752f));
}

// ---------------- f32 tile transpose: in[R][C] -> out[C][R] ----------------------
// grid (C/64, R/64), block 256
__global__ __launch_bounds__(256) void k_tr(const float* __restrict__ in,
                                            float* __restrict__ out, int R, int C) {
    __shared__ float T[64][65];
    int r0 = blockIdx.y * 64, c0 = blockIdx.x * 64;
    int t = threadIdx.x;
    int rr = t >> 4, cc = (t & 15) * 4;
#pragma unroll
    for (int i = 0; i < 4; ++i) {
        int row = i * 16 + rr;
        float4 v = *(const float4*)(in + (size_t)(r0 + row) * C + c0 + cc);
        T[row][cc] = v.x; T[row][cc + 1] = v.y; T[row][cc + 2] = v.z; T[row][cc + 3] = v.w;
    }
    __syncthreads();
#pragma unroll
    for (int i = 0; i < 4; ++i) {
        int a = i * 16 + rr;
        float4 v;
        v.x = T[cc][a]; v.y = T[cc + 1][a]; v.z = T[cc + 2][a]; v.w = T[cc + 3][a];
        *(float4*)(out + (size_t)(c0 + a) * R + r0 + cc) = v;
    }
}

// ---------------- bilinear 16x downsample (1024->64) -----------------------------
__global__ void k_down(const float* __restrict__ x, float* __restrict__ xd) {
    int t = blockIdx.x * 256 + threadIdx.x;
    int i = t >> 6, j = t & 63;
    int r0 = 16 * i + 7, c0 = 16 * j + 7;
    float v = x[r0 * 1024 + c0] + x[r0 * 1024 + c0 + 1] +
              x[(r0 + 1) * 1024 + c0] + x[(r0 + 1) * 1024 + c0 + 1];
    xd[t] = 0.25f * v;
}

// ---------------- conv3x3 (1->256) + ReLU, token-major bf16 out ------------------
// grid 256 (16 tokens each, one row), block 256 (one thread per out channel)
__global__ __launch_bounds__(256) void k_pe3(const float* __restrict__ xd,
                                             const float* __restrict__ w,
                                             const float* __restrict__ b,
                                             u16* __restrict__ y) {
    __shared__ float nb[3][18];
    int n0 = blockIdx.x * 16;
    int yy = n0 >> 6, x0 = n0 & 63;
    int t = threadIdx.x;
    if (t < 54) {
        int r = t / 18, cc = t % 18;
        int sy = yy - 1 + r, sx = x0 - 1 + cc;
        nb[r][cc] = (sy >= 0 && sy < 64 && sx >= 0 && sx < 64) ? xd[sy * 64 + sx] : 0.f;
    }
    __syncthreads();
    float wv[9];
#pragma unroll
    for (int i = 0; i < 9; ++i) wv[i] = w[t * 9 + i];
    float bb = b[t];
#pragma unroll
    for (int k = 0; k < 16; ++k) {
        float acc = bb;
#pragma unroll
        for (int r = 0; r < 3; ++r)
#pragma unroll
            for (int kx = 0; kx < 3; ++kx) acc += wv[r * 3 + kx] * nb[r][k + kx];
        y[(size_t)(n0 + k) * CDIM + t] = f2bf(fmaxf(acc, 0.f));
    }
}

// ---------------- token-major LayerNorm over channels ----------------------------
// grid 1024, block 256 (4 waves = 4 tokens; lane owns 4 channels)
__global__ __launch_bounds__(256) void k_lnT(const void* __restrict__ x, int xf32,
                                             const float* __restrict__ g,
                                             const float* __restrict__ b,
                                             const u16* __restrict__ pe,
                                             const float* __restrict__ pos,
                                             void* __restrict__ y, int yf32) {
    int n = blockIdx.x * 4 + (threadIdx.x >> 6);
    int lane = threadIdx.x & 63;
    int c = lane * 4;
    float4 xv;
    if (xf32) {
        xv = *((const float4*)x + (size_t)n * 64 + lane);
    } else {
        ushort4 u = *((const ushort4*)x + (size_t)n * 64 + lane);
        xv = make_float4(bf2f(u.x), bf2f(u.y), bf2f(u.z), bf2f(u.w));
    }
    float s = xv.x + xv.y + xv.z + xv.w;
    float s2 = xv.x * xv.x + xv.y * xv.y + xv.z * xv.z + xv.w * xv.w;
#pragma unroll
    for (int off = 1; off < 64; off <<= 1) {
        s += __shfl_xor(s, off, 64);
        s2 += __shfl_xor(s2, off, 64);
    }
    float mu = s * (1.0f / 256.0f);
    float var = s2 * (1.0f / 256.0f) - mu * mu;
    float rsd = rsqrtf(var + EPS_LN);
    float4 g4 = *(const float4*)(g + c);
    float4 b4 = *(const float4*)(b + c);
    float4 o;
    o.x = (xv.x - mu) * rsd * g4.x + b4.x;
    o.y = (xv.y - mu) * rsd * g4.y + b4.y;
    o.z = (xv.z - mu) * rsd * g4.z + b4.z;
    o.w = (xv.w - mu) * rsd * g4.w + b4.w;
    if (pe) {
        float4 p4 = *(const float4*)(pos + c);
        ushort4 pu = *((const ushort4*)pe + (size_t)n * 64 + lane);
        o.x += p4.x + bf2f(pu.x);
        o.y += p4.y + bf2f(pu.y);
        o.z += p4.z + bf2f(pu.z);
        o.w += p4.w + bf2f(pu.w);
    }
    if (yf32) {
        *((float4*)y + (size_t)n * 64 + lane) = o;
    } else {
        ushort4 ou;
        ou.x = f2bf(o.x); ou.y = f2bf(o.y); ou.z = f2bf(o.z); ou.w = f2bf(o.w);
        *((ushort4*)y + (size_t)n * 64 + lane) = ou;
    }
}

// ---------------- bf16 MFMA GEMM: Y[n][m] = sum_k X[n][k]*W[m][k] ----------------
// X bf16 token-major [4096][K]; W f32 [M][K] (converted to bf16 in staging).
// flags: 1=GELU, 2=swap output -> Y[m][4096], 4=res f32 [N][M], 8=res bf16 [N][M],
//        16=scale (acc+bias)*log2e/scl[0]
// grid (4096/64, M/64), block 256 (4 waves, 2x2 of 32tok x 32ch)
#define LDB 72
__global__ __launch_bounds__(256) void k_bmm(const u16* __restrict__ X,
                                             const float* __restrict__ W,
                                             const float* __restrict__ bias,
                                             const void* __restrict__ res,
                                             u16* __restrict__ Y,
                                             int M, int K, int flags,
                                             const float* __restrict__ scl) {
    __shared__ u16 Xs[64 * LDB];
    __shared__ u16 Ws[64 * LDB];
    int tid = threadIdx.x;
    int wid = tid >> 6, lane = tid & 63;
    int lo16 = lane & 15, quad = lane >> 4;
    int wy = wid & 1, wx = wid >> 1;
    int n0 = blockIdx.x * 64, m0 = blockIdx.y * 64;
    int srow = tid >> 2, sseg = tid & 3;

    floatx4 acc[2][2];
#pragma unroll
    for (int i = 0; i < 2; ++i)
#pragma unroll
        for (int j = 0; j < 2; ++j) acc[i][j] = floatx4{0.f, 0.f, 0.f, 0.f};

    for (int k0 = 0; k0 < K; k0 += 64) {
        const u16* xp = X + (size_t)(n0 + srow) * K + k0 + sseg * 16;
        uint4 xr0 = *(const uint4*)xp;
        uint4 xr1 = *(const uint4*)(xp + 8);
        const float* wp = W + (size_t)(m0 + srow) * K + k0 + sseg * 16;
        float4 w0 = *(const float4*)wp;
        float4 w1 = *(const float4*)(wp + 4);
        float4 w2 = *(const float4*)(wp + 8);
        float4 w3 = *(const float4*)(wp + 12);
        if (k0) __syncthreads();
        *(uint4*)&Xs[srow * LDB + sseg * 16] = xr0;
        *(uint4*)&Xs[srow * LDB + sseg * 16 + 8] = xr1;
        uint4 wb0, wb1;
        wb0.x = pkbf(w0.x, w0.y); wb0.y = pkbf(w0.z, w0.w);
        wb0.z = pkbf(w1.x, w1.y); wb0.w = pkbf(w1.z, w1.w);
        wb1.x = pkbf(w2.x, w2.y); wb1.y = pkbf(w2.z, w2.w);
        wb1.z = pkbf(w3.x, w3.y); wb1.w = pkbf(w3.z, w3.w);
        *(uint4*)&Ws[srow * LDB + sseg * 16] = wb0;
        *(uint4*)&Ws[srow * LDB + sseg * 16 + 8] = wb1;
        __syncthreads();

        const u16* As = (flags & 2) ? Ws : Xs;
        const u16* Bs = (flags & 2) ? Xs : Ws;
#pragma unroll
        for (int h = 0; h < 2; ++h) {
            int ko = h * 32 + quad * 8;
            bf16x8 a0 = *(const bf16x8*)&As[(wy * 32 + lo16) * LDB + ko];
            bf16x8 a1 = *(const bf16x8*)&As[(wy * 32 + 16 + lo16) * LDB + ko];
            bf16x8 b0 = *(const bf16x8*)&Bs[(wx * 32 + lo16) * LDB + ko];
            bf16x8 b1 = *(const bf16x8*)&Bs[(wx * 32 + 16 + lo16) * LDB + ko];
            acc[0][0] = __builtin_amdgcn_mfma_f32_16x16x32_bf16(a0, b0, acc[0][0], 0, 0, 0);
            acc[0][1] = __builtin_amdgcn_mfma_f32_16x16x32_bf16(a0, b1, acc[0][1], 0, 0, 0);
            acc[1][0] = __builtin_amdgcn_mfma_f32_16x16x32_bf16(a1, b0, acc[1][0], 0, 0, 0);
            acc[1][1] = __builtin_amdgcn_mfma_f32_16x16x32_bf16(a1, b1, acc[1][1], 0, 0, 0);
        }
    }

    if (flags & 2) {
        // swap: A-tiles = channels, B-tiles = tokens; Y[m][4096]
#pragma unroll
        for (int i = 0; i < 2; ++i)
#pragma unroll
            for (int r = 0; r < 4; ++r) {
                int ch = m0 + wy * 32 + i * 16 + quad * 4 + r;
                float bb = bias[ch];
#pragma unroll
                for (int j = 0; j < 2; ++j) {
                    int tok = n0 + wx * 32 + j * 16 + lo16;
                    Y[(size_t)ch * NTOK + tok] = f2bf(acc[i][j][r] + bb);
                }
            }
    } else {
        float smul = 1.0f;
        if (flags & 16) smul = 1.4426950408889634f / scl[0];
        float bj0 = bias[m0 + wx * 32 + lo16];
        float bj1 = bias[m0 + wx * 32 + 16 + lo16];
        const float* rf = (const float*)res;
        const u16* rb = (const u16*)res;
#pragma unroll
        for (int i = 0; i < 2; ++i)
#pragma unroll
            for (int j = 0; j < 2; ++j) {
                int ch = m0 + wx * 32 + j * 16 + lo16;
                float bb = j ? bj1 : bj0;
#pragma unroll
                for (int r = 0; r < 4; ++r) {
                    int tok = n0 + wy * 32 + i * 16 + quad * 4 + r;
                    float v = (acc[i][j][r] + bb) * smul;
                    if (flags & 1) v = gelu_exact(v);
                    if (flags & 4) v += rf[(size_t)tok * M + ch];
                    if (flags & 8) v += bf2f(rb[(size_t)tok * M + ch]);
                    Y[(size_t)tok * M + ch] = f2bf(v);
                }
            }
    }
}

// ---------------- bf16 MFMA flash attention (swapped operands) -------------------
// q,k: token-major [4096][256] bf16 (q pre-scaled by log2e/scale);
// v: channel-major [256][4096] bf16; out: token-major [4096][256] bf16.
// grid (64, 8), block 256 = 4 waves x 16 queries.
#define LDK 40
#define LDV 72
__global__ __launch_bounds__(256) void k_fattn(const u16* __restrict__ qbf,
                                               const u16* __restrict__ kbf,
                                               const u16* __restrict__ vbf,
                                               u16* __restrict__ outT) {
    int h = blockIdx.y;
    int q0 = blockIdx.x * 64;
    int tid = threadIdx.x;
    int wid = tid >> 6, lane = tid & 63;
    int lo16 = lane & 15, quad = lane >> 4;

    __shared__ u16 Kt[64 * LDK];
    __shared__ u16 Vt[32 * LDV];
    __shared__ u16 Pt[4][16 * LDV];

    // Q fragment (B-operand): col = q (lo16 within wave group), k = d
    bf16x8 aq = *(const bf16x8*)(qbf + (size_t)(q0 + wid * 16 + lo16) * CDIM + h * 32 + quad * 8);

    floatx4 o0 = {0.f, 0.f, 0.f, 0.f};
    floatx4 o1 = {0.f, 0.f, 0.f, 0.f};
    float mrun = -1e30f, lrun = 0.f;

    int krow = tid >> 2, kseg = tid & 3;
    int vrow = tid >> 3, vseg = tid & 7;

    for (int kt = 0; kt < NTOK / 64; ++kt) {
        int k0 = kt * 64;
        uint4 kreg = *(const uint4*)(kbf + (size_t)(k0 + krow) * CDIM + h * 32 + kseg * 8);
        uint4 vreg = *(const uint4*)(vbf + (size_t)(h * 32 + vrow) * NTOK + k0 + vseg * 8);
        __syncthreads();
        *(uint4*)&Kt[krow * LDK + kseg * 8] = kreg;
        *(uint4*)&Vt[vrow * LDV + vseg * 8] = vreg;
        __syncthreads();

        // S^T = K Q^T: rows = keys, cols = q. Lane: q=lo16, keys c*16+quad*4+r.
        floatx4 s[4];
        floatx4 z = {0.f, 0.f, 0.f, 0.f};
#pragma unroll
        for (int c = 0; c < 4; ++c) {
            bf16x8 ak = *(const bf16x8*)&Kt[(c * 16 + lo16) * LDK + quad * 8];
            s[c] = __builtin_amdgcn_mfma_f32_16x16x32_bf16(ak, aq, z, 0, 0, 0);
        }
        // online softmax for q = lo16 (s already in log2 domain)
        float mx = s[0][0];
#pragma unroll
        for (int c = 0; c < 4; ++c)
#pragma unroll
            for (int r = 0; r < 4; ++r) mx = fmaxf(mx, s[c][r]);
        mx = fmaxf(mx, __shfl_xor(mx, 16, 64));
        mx = fmaxf(mx, __shfl_xor(mx, 32, 64));
        float mnew = fmaxf(mrun, mx);
        float alpha = __builtin_amdgcn_exp2f(mrun - mnew);
        mrun = mnew;
        float rs = 0.f;
#pragma unroll
        for (int c = 0; c < 4; ++c)
#pragma unroll
            for (int r = 0; r < 4; ++r) {
                float p = __builtin_amdgcn_exp2f(s[c][r] - mnew);
                s[c][r] = p;
                rs += p;
            }
        rs += __shfl_xor(rs, 16, 64);
        rs += __shfl_xor(rs, 32, 64);
        lrun = lrun * alpha + rs;
        // pack P (4 consecutive keys per reg) -> Pt[q][key], one b64 per c-tile
#pragma unroll
        for (int c = 0; c < 4; ++c) {
            uint2 w;
            w.x = pkbf(s[c][0], s[c][1]);
            w.y = pkbf(s[c][2], s[c][3]);
            *(uint2*)&Pt[wid][lo16 * LDV + c * 16 + quad * 4] = w;
        }
        o0 *= alpha;
        o1 *= alpha;
        // O^T += V P: rows = d, cols = q (alpha/l lane-local at col q=lo16)
#pragma unroll
        for (int kc = 0; kc < 2; ++kc) {
            bf16x8 bp = *(const bf16x8*)&Pt[wid][lo16 * LDV + kc * 32 + quad * 8];
            bf16x8 av0 = *(const bf16x8*)&Vt[lo16 * LDV + kc * 32 + quad * 8];
            bf16x8 av1 = *(const bf16x8*)&Vt[(16 + lo16) * LDV + kc * 32 + quad * 8];
            o0 = __builtin_amdgcn_mfma_f32_16x16x32_bf16(av0, bp, o0, 0, 0, 0);
            o1 = __builtin_amdgcn_mfma_f32_16x16x32_bf16(av1, bp, o1, 0, 0, 0);
        }
    }

    // epilogue: O /= l; transpose to token-major via LDS, coalesced store
    float inv = 1.0f / lrun;
    __syncthreads();
    u16* Ot = Kt;  // reuse (64*40 u16)
    int q = wid * 16 + lo16;
    {
        uint2 w;
        w.x = pkbf(o0[0] * inv, o0[1] * inv);
        w.y = pkbf(o0[2] * inv, o0[3] * inv);
        *(uint2*)&Ot[q * LDK + quad * 4] = w;
        w.x = pkbf(o1[0] * inv, o1[1] * inv);
        w.y = pkbf(o1[2] * inv, o1[3] * inv);
        *(uint2*)&Ot[q * LDK + 16 + quad * 4] = w;
    }
    __syncthreads();
    int orow = tid >> 2, oseg = tid & 3;
    uint4 ov = *(const uint4*)&Ot[orow * LDK + oseg * 8];
    *(uint4*)(outT + (size_t)(q0 + orow) * CDIM + h * 32 + oseg * 8) = ov;
}

// ------------------------------------------------------------------------------
extern "C" void kernel_launch(void* const* d_in, const int* in_sizes, int n_in,
                              void* d_out, int out_size, void* d_ws, size_t ws_size,
                              hipStream_t stream) {
    const float* rgb    = (const float*)d_in[0];
    const float* dpt    = (const float*)d_in[1];
    const float* x_dpt  = (const float*)d_in[2];
    const float* wq     = (const float*)d_in[3];
    const float* bq     = (const float*)d_in[4];
    const float* wk     = (const float*)d_in[5];
    const float* bk     = (const float*)d_in[6];
    const float* wv     = (const float*)d_in[7];
    const float* bv     = (const float*)d_in[8];
    const float* wo     = (const float*)d_in[9];
    const float* bo     = (const float*)d_in[10];
    const float* g_rgb  = (const float*)d_in[11];
    const float* b_rgb  = (const float*)d_in[12];
    const float* g_dpt  = (const float*)d_in[13];
    const float* b_dpt  = (const float*)d_in[14];
    const float* g1     = (const float*)d_in[15];
    const float* b1     = (const float*)d_in[16];
    const float* g2     = (const float*)d_in[17];
    const float* b2     = (const float*)d_in[18];
    const float* w_mlp1 = (const float*)d_in[19];
    const float* b_mlp1 = (const float*)d_in[20];
    const float* w_mlp2 = (const float*)d_in[21];
    const float* b_mlp2 = (const float*)d_in[22];
    const float* w_de1  = (const float*)d_in[23];
    const float* b_de1  = (const float*)d_in[24];
    const float* w_de2  = (const float*)d_in[25];
    const float* b_de2  = (const float*)d_in[26];
    const float* pos    = (const float*)d_in[27];
    const float* scale  = (const float*)d_in[28];
    float* out = (float*)d_out;

    float* ws = (float*)d_ws;
    const size_t F = (size_t)NTOK * CDIM;      // 1M floats = 4 MB (f32 buffer)
    const size_t Hh = F / 2;                   // bf16 buffer = 2 MB = 0.5M floats

    float* rgbT   = ws;                        // f32 [N][C]
    float* dptT   = ws + F;                    // f32 [N][C]
    u16* relu3T   = (u16*)(ws + 2 * F);        // bf16 [N][C]
    u16* peT      = (u16*)(ws + 2 * F + Hh);   // bf16 [N][C]
    u16* aqT      = (u16*)(ws + 3 * F);        // bf16 [N][C]
    u16* akvT     = (u16*)(ws + 3 * F + Hh);   // bf16 [N][C]
    u16* q_bf     = (u16*)(ws + 4 * F);        // bf16 [N][C]
    u16* k_bf     = (u16*)(ws + 4 * F + Hh);   // bf16 [N][C]
    u16* v_bf     = (u16*)(ws + 5 * F);        // bf16 [C][N]
    u16* fusedT   = (u16*)(ws + 5 * F + Hh);   // bf16 [N][C]
    u16* outT     = (u16*)(ws + F);            // reuse dptT after LNs
    u16* out_lnT  = (u16*)(ws + F) + Hh;       // (u16 elements) second half of dptT slot
    u16* hT       = (u16*)(ws + 2 * F);        // bf16 [N][1024] = 8 MB (reuses relu3T..akvT)
    u16* out2T    = (u16*)(ws + 4 * F);        // reuse q/k slot
    float* lnoutT = ws + 5 * F;                // f32 [N][C] (reuse v/fused slot)
    float* xd     = ws + 6 * F;                // 4096 floats

    dim3 g256(NTOK / 64, CDIM / 64);           // (64, 4)
    dim3 g1024(NTOK / 64, MLPD / 64);          // (64, 16)

    // transposes to token-major
    k_tr<<<dim3(NTOK / 64, CDIM / 64), 256, 0, stream>>>(rgb, rgbT, CDIM, NTOK);
    k_tr<<<dim3(NTOK / 64, CDIM / 64), 256, 0, stream>>>(dpt, dptT, CDIM, NTOK);

    // depth positional embedding
    k_down<<<16, 256, 0, stream>>>(x_dpt, xd);
    k_pe3<<<256, 256, 0, stream>>>(xd, w_de1, b_de1, relu3T);
    k_bmm<<<g256, 256, 0, stream>>>(relu3T, w_de2, b_de2, nullptr, peT, CDIM, CDIM, 0, nullptr);

    // layernorms + pos + pe -> bf16 token-major
    k_lnT<<<1024, 256, 0, stream>>>(rgbT, 1, g_rgb, b_rgb, peT, pos, aqT, 0);
    k_lnT<<<1024, 256, 0, stream>>>(dptT, 1, g_dpt, b_dpt, peT, pos, akvT, 0);

    // qkv projections (q folds log2e/scale; v emitted channel-major)
    k_bmm<<<g256, 256, 0, stream>>>(aqT, wq, bq, nullptr, q_bf, CDIM, CDIM, 16, scale);
    k_bmm<<<g256, 256, 0, stream>>>(akvT, wk, bk, nullptr, k_bf, CDIM, CDIM, 0, nullptr);
    k_bmm<<<g256, 256, 0, stream>>>(akvT, wv, bv, nullptr, v_bf, CDIM, CDIM, 2, nullptr);

    // flash attention -> fusedT bf16 [N][C]
    k_fattn<<<dim3(NTOK / 64, 8), 256, 0, stream>>>(q_bf, k_bf, v_bf, fusedT);

    // output projection + residual(rgbT f32) -> outT bf16
    k_bmm<<<g256, 256, 0, stream>>>(fusedT, wo, bo, rgbT, outT, CDIM, CDIM, 4, nullptr);
    k_lnT<<<1024, 256, 0, stream>>>(outT, 0, g1, b1, nullptr, nullptr, out_lnT, 0);

    // MLP
    k_bmm<<<g1024, 256, 0, stream>>>(out_lnT, w_mlp1, b_mlp1, nullptr, hT, MLPD, CDIM, 1, nullptr);
    k_bmm<<<g256, 256, 0, stream>>>(hT, w_mlp2, b_mlp2, out_lnT, out2T, CDIM, MLPD, 8, nullptr);

    // final LN (f32) + transpose to [C][N]
    k_lnT<<<1024, 256, 0, stream>>>(out2T, 0, g2, b2, nullptr, nullptr, lnoutT, 1);
    k_tr<<<dim3(CDIM / 64, NTOK / 64), 256, 0, stream>>>(lnoutT, out, NTOK, CDIM);
}

// Round 4
// 226.859 us; speedup vs baseline: 17.1888x; 1.1794x over previous
//
#include <hip/hip_runtime.h>
#include <hip/hip_bf16.h>
#include <math.h>

constexpr int NTOK = 4096;
constexpr int CDIM = 256;
constexpr int MLPD = 1024;
constexpr int SPLIT = 4;
constexpr float EPS_LN = 1e-5f;

typedef __attribute__((ext_vector_type(8))) short bf16x8;
typedef __attribute__((ext_vector_type(4))) float floatx4;
typedef unsigned short u16;
typedef unsigned int u32;

__device__ __forceinline__ u16 f2bf(float x) {
    union { float f; u32 u; } v; v.f = x;
    u32 r = v.u + 0x7fff + ((v.u >> 16) & 1);
    return (u16)(r >> 16);
}
__device__ __forceinline__ float bf2f(u16 u) {
    union { u32 i; float f; } v; v.i = ((u32)u) << 16; return v.f;
}
__device__ __forceinline__ u32 pkbf(float a, float b) {
    __hip_bfloat162 h = __float22bfloat162_rn(make_float2(a, b));
    union { __hip_bfloat162 h; u32 u; } v; v.h = h; return v.u;
}
__device__ __forceinline__ float gelu_exact(float x) {
    return 0.5f * x * (1.0f + erff(x * 0.70710678118654752f));
}

// ---------------- f32 transpose (dual-input): in[R][C] -> out[C][R] --------------
__global__ __launch_bounds__(256) void k_tr2(const float* __restrict__ in0,
                                             float* __restrict__ out0,
                                             const float* __restrict__ in1,
                                             float* __restrict__ out1, int R, int C) {
    const float* in = blockIdx.z ? in1 : in0;
    float* out = blockIdx.z ? out1 : out0;
    __shared__ float T[64][65];
    int r0 = blockIdx.y * 64, c0 = blockIdx.x * 64;
    int t = threadIdx.x;
    int rr = t >> 4, cc = (t & 15) * 4;
#pragma unroll
    for (int i = 0; i < 4; ++i) {
        int row = i * 16 + rr;
        float4 v = *(const float4*)(in + (size_t)(r0 + row) * C + c0 + cc);
        T[row][cc] = v.x; T[row][cc + 1] = v.y; T[row][cc + 2] = v.z; T[row][cc + 3] = v.w;
    }
    __syncthreads();
#pragma unroll
    for (int i = 0; i < 4; ++i) {
        int a = i * 16 + rr;
        float4 v;
        v.x = T[cc][a]; v.y = T[cc + 1][a]; v.z = T[cc + 2][a]; v.w = T[cc + 3][a];
        *(float4*)(out + (size_t)(c0 + a) * R + r0 + cc) = v;
    }
}

// ---------------- prep: blocks 0-255 = downsample+conv3x3+relu; 256+ = W->bf16 ---
__global__ __launch_bounds__(256) void k_prep(const float* __restrict__ xdpt,
                                              const float* __restrict__ w3,
                                              const float* __restrict__ b3,
                                              u16* __restrict__ y,
                                              const float* __restrict__ wq,
                                              const float* __restrict__ wk,
                                              const float* __restrict__ wv,
                                              const float* __restrict__ wo,
                                              const float* __restrict__ wde2,
                                              const float* __restrict__ wm1,
                                              const float* __restrict__ wm2,
                                              u16* __restrict__ arena) {
    int blk = blockIdx.x;
    int t = threadIdx.x;
    if (blk < 256) {
        __shared__ float nb[3][18];
        int n0 = blk * 16;
        int yy = n0 >> 6, x0 = n0 & 63;
        if (t < 54) {
            int r = t / 18, cc = t % 18;
            int sy = yy - 1 + r, sx = x0 - 1 + cc;
            float v = 0.f;
            if (sy >= 0 && sy < 64 && sx >= 0 && sx < 64) {
                int r0 = 16 * sy + 7, c0 = 16 * sx + 7;
                v = 0.25f * (xdpt[r0 * 1024 + c0] + xdpt[r0 * 1024 + c0 + 1] +
                             xdpt[(r0 + 1) * 1024 + c0] + xdpt[(r0 + 1) * 1024 + c0 + 1]);
            }
            nb[r][cc] = v;
        }
        __syncthreads();
        float wv9[9];
#pragma unroll
        for (int i = 0; i < 9; ++i) wv9[i] = w3[t * 9 + i];
        float bb = b3[t];
#pragma unroll
        for (int k = 0; k < 16; ++k) {
            float acc = bb;
#pragma unroll
            for (int r = 0; r < 3; ++r)
#pragma unroll
                for (int kx = 0; kx < 3; ++kx) acc += wv9[r * 3 + kx] * nb[r][k + kx];
            y[(size_t)(n0 + k) * CDIM + t] = f2bf(fmaxf(acc, 0.f));
        }
    } else {
        int e0 = (blk - 256) * 1024 + t * 4;
        const float* src; int off;
        if (e0 < 65536)       { src = wq;   off = 0; }
        else if (e0 < 131072) { src = wk;   off = 65536; }
        else if (e0 < 196608) { src = wv;   off = 131072; }
        else if (e0 < 262144) { src = wo;   off = 196608; }
        else if (e0 < 327680) { src = wde2; off = 262144; }
        else if (e0 < 589824) { src = wm1;  off = 327680; }
        else                  { src = wm2;  off = 589824; }
        float4 v = *(const float4*)(src + (e0 - off));
        uint2 o; o.x = pkbf(v.x, v.y); o.y = pkbf(v.z, v.w);
        *(uint2*)(arena + e0) = o;
    }
}

// ---------------- token-major LayerNorm (dual-set via blockIdx.y) ----------------
__global__ __launch_bounds__(256) void k_lnT(const void* __restrict__ xA,
                                             const float* __restrict__ gA,
                                             const float* __restrict__ bA,
                                             void* __restrict__ yA,
                                             const void* __restrict__ xB,
                                             const float* __restrict__ gB,
                                             const float* __restrict__ bB,
                                             void* __restrict__ yB,
                                             const u16* __restrict__ pe,
                                             const float* __restrict__ pos,
                                             int xf32, int yf32) {
    const void* x; const float* g; const float* bb; void* y;
    if (blockIdx.y == 0) { x = xA; g = gA; bb = bA; y = yA; }
    else                 { x = xB; g = gB; bb = bB; y = yB; }
    int n = blockIdx.x * 4 + (threadIdx.x >> 6);
    int lane = threadIdx.x & 63;
    int c = lane * 4;
    float4 xv;
    if (xf32) {
        xv = *((const float4*)x + (size_t)n * 64 + lane);
    } else {
        ushort4 u = *((const ushort4*)x + (size_t)n * 64 + lane);
        xv = make_float4(bf2f(u.x), bf2f(u.y), bf2f(u.z), bf2f(u.w));
    }
    float s = xv.x + xv.y + xv.z + xv.w;
    float s2 = xv.x * xv.x + xv.y * xv.y + xv.z * xv.z + xv.w * xv.w;
#pragma unroll
    for (int off = 1; off < 64; off <<= 1) {
        s += __shfl_xor(s, off, 64);
        s2 += __shfl_xor(s2, off, 64);
    }
    float mu = s * (1.0f / 256.0f);
    float var = s2 * (1.0f / 256.0f) - mu * mu;
    float rsd = rsqrtf(var + EPS_LN);
    float4 g4 = *(const float4*)(g + c);
    float4 b4 = *(const float4*)(bb + c);
    float4 o;
    o.x = (xv.x - mu) * rsd * g4.x + b4.x;
    o.y = (xv.y - mu) * rsd * g4.y + b4.y;
    o.z = (xv.z - mu) * rsd * g4.z + b4.z;
    o.w = (xv.w - mu) * rsd * g4.w + b4.w;
    if (pe) {
        float4 p4 = *(const float4*)(pos + c);
        ushort4 pu = *((const ushort4*)pe + (size_t)n * 64 + lane);
        o.x += p4.x + bf2f(pu.x);
        o.y += p4.y + bf2f(pu.y);
        o.z += p4.z + bf2f(pu.z);
        o.w += p4.w + bf2f(pu.w);
    }
    if (yf32) {
        *((float4*)y + (size_t)n * 64 + lane) = o;
    } else {
        ushort4 ou;
        ou.x = f2bf(o.x); ou.y = f2bf(o.y); ou.z = f2bf(o.z); ou.w = f2bf(o.w);
        *((ushort4*)y + (size_t)n * 64 + lane) = ou;
    }
}

// ---------------- bf16 MFMA GEMM (3-way select via blockIdx.z) -------------------
// Y[n][m] = sum_k X[n][k]*W[m][k]; X bf16 [4096][K]; W f32 or bf16 (flag 32).
// flags: 1 GELU | 2 swap-out [m][4096] | 4 res f32 [N][M] | 8 res bf16 [N][M]
//      | 16 smul=log2e/scl | 32 W bf16 | 64 head-major out [m>>5][tok][m&31]
#define LDB 72
__global__ __launch_bounds__(256) void k_bmm(const u16* __restrict__ X0, const void* __restrict__ W0,
                                             const float* __restrict__ B0, void* __restrict__ Y0, int f0,
                                             const u16* __restrict__ X1, const void* __restrict__ W1,
                                             const float* __restrict__ B1, void* __restrict__ Y1, int f1,
                                             const u16* __restrict__ X2, const void* __restrict__ W2,
                                             const float* __restrict__ B2, void* __restrict__ Y2, int f2,
                                             const void* __restrict__ res, const float* __restrict__ scl,
                                             int M, int K) {
    const u16* X; const void* Wp; const float* bias; void* Yp; int flags;
    if (blockIdx.z == 0)      { X = X0; Wp = W0; bias = B0; Yp = Y0; flags = f0; }
    else if (blockIdx.z == 1) { X = X1; Wp = W1; bias = B1; Yp = Y1; flags = f1; }
    else                      { X = X2; Wp = W2; bias = B2; Yp = Y2; flags = f2; }
    __shared__ u16 Xs[64 * LDB];
    __shared__ u16 Ws[64 * LDB];
    int tid = threadIdx.x;
    int wid = tid >> 6, lane = tid & 63;
    int lo16 = lane & 15, quad = lane >> 4;
    int wy = wid & 1, wx = wid >> 1;
    int n0 = blockIdx.x * 64, m0 = blockIdx.y * 64;
    int srow = tid >> 2, sseg = tid & 3;

    floatx4 acc[2][2];
#pragma unroll
    for (int i = 0; i < 2; ++i)
#pragma unroll
        for (int j = 0; j < 2; ++j) acc[i][j] = floatx4{0.f, 0.f, 0.f, 0.f};

    for (int k0 = 0; k0 < K; k0 += 64) {
        const u16* xp = X + (size_t)(n0 + srow) * K + k0 + sseg * 16;
        uint4 xr0 = *(const uint4*)xp;
        uint4 xr1 = *(const uint4*)(xp + 8);
        uint4 wb0, wb1;
        if (flags & 32) {
            const u16* wp = (const u16*)Wp + (size_t)(m0 + srow) * K + k0 + sseg * 16;
            wb0 = *(const uint4*)wp;
            wb1 = *(const uint4*)(wp + 8);
        } else {
            const float* wp = (const float*)Wp + (size_t)(m0 + srow) * K + k0 + sseg * 16;
            float4 w0 = *(const float4*)wp;
            float4 w1 = *(const float4*)(wp + 4);
            float4 w2 = *(const float4*)(wp + 8);
            float4 w3 = *(const float4*)(wp + 12);
            wb0.x = pkbf(w0.x, w0.y); wb0.y = pkbf(w0.z, w0.w);
            wb0.z = pkbf(w1.x, w1.y); wb0.w = pkbf(w1.z, w1.w);
            wb1.x = pkbf(w2.x, w2.y); wb1.y = pkbf(w2.z, w2.w);
            wb1.z = pkbf(w3.x, w3.y); wb1.w = pkbf(w3.z, w3.w);
        }
        if (k0) __syncthreads();
        *(uint4*)&Xs[srow * LDB + sseg * 16] = xr0;
        *(uint4*)&Xs[srow * LDB + sseg * 16 + 8] = xr1;
        *(uint4*)&Ws[srow * LDB + sseg * 16] = wb0;
        *(uint4*)&Ws[srow * LDB + sseg * 16 + 8] = wb1;
        __syncthreads();

        const u16* As = (flags & 2) ? Ws : Xs;
        const u16* Bs = (flags & 2) ? Xs : Ws;
#pragma unroll
        for (int h = 0; h < 2; ++h) {
            int ko = h * 32 + quad * 8;
            bf16x8 a0 = *(const bf16x8*)&As[(wy * 32 + lo16) * LDB + ko];
            bf16x8 a1 = *(const bf16x8*)&As[(wy * 32 + 16 + lo16) * LDB + ko];
            bf16x8 b0 = *(const bf16x8*)&Bs[(wx * 32 + lo16) * LDB + ko];
            bf16x8 b1 = *(const bf16x8*)&Bs[(wx * 32 + 16 + lo16) * LDB + ko];
            acc[0][0] = __builtin_amdgcn_mfma_f32_16x16x32_bf16(a0, b0, acc[0][0], 0, 0, 0);
            acc[0][1] = __builtin_amdgcn_mfma_f32_16x16x32_bf16(a0, b1, acc[0][1], 0, 0, 0);
            acc[1][0] = __builtin_amdgcn_mfma_f32_16x16x32_bf16(a1, b0, acc[1][0], 0, 0, 0);
            acc[1][1] = __builtin_amdgcn_mfma_f32_16x16x32_bf16(a1, b1, acc[1][1], 0, 0, 0);
        }
    }

    u16* Y = (u16*)Yp;
    if (flags & 2) {
#pragma unroll
        for (int i = 0; i < 2; ++i)
#pragma unroll
            for (int r = 0; r < 4; ++r) {
                int ch = m0 + wy * 32 + i * 16 + quad * 4 + r;
                float bb = bias[ch];
#pragma unroll
                for (int j = 0; j < 2; ++j) {
                    int tok = n0 + wx * 32 + j * 16 + lo16;
                    Y[(size_t)ch * NTOK + tok] = f2bf(acc[i][j][r] + bb);
                }
            }
    } else {
        float smul = (flags & 16) ? 1.4426950408889634f / scl[0] : 1.0f;
        float bj0 = bias[m0 + wx * 32 + lo16];
        float bj1 = bias[m0 + wx * 32 + 16 + lo16];
        const float* rf = (const float*)res;
        const u16* rb = (const u16*)res;
#pragma unroll
        for (int i = 0; i < 2; ++i)
#pragma unroll
            for (int j = 0; j < 2; ++j) {
                int ch = m0 + wx * 32 + j * 16 + lo16;
                float bb = j ? bj1 : bj0;
#pragma unroll
                for (int r = 0; r < 4; ++r) {
                    int tok = n0 + wy * 32 + i * 16 + quad * 4 + r;
                    float v = (acc[i][j][r] + bb) * smul;
                    if (flags & 1) v = gelu_exact(v);
                    if (flags & 4) v += rf[(size_t)tok * M + ch];
                    if (flags & 8) v += bf2f(rb[(size_t)tok * M + ch]);
                    if (flags & 64)
                        Y[((size_t)(ch >> 5) * NTOK + tok) * 32 + (ch & 31)] = f2bf(v);
                    else
                        Y[(size_t)tok * M + ch] = f2bf(v);
                }
            }
    }
}

// ---------------- split-K flash attention, no-max softmax ------------------------
// Q,K head-major [h][tok][32] bf16 (Q pre-scaled by log2e/scale); V [c][n] bf16.
// Partials: Op bf16 [s][h][tok][32], Lp f32 [s][h][tok].
// grid (64, 8, SPLIT), block 256 = 4 waves x 16 queries.
#define LDK 40
#define LDV 72
__global__ __launch_bounds__(256, 8) void k_fattn(const u16* __restrict__ Qh,
                                                  const u16* __restrict__ Kh,
                                                  const u16* __restrict__ Vc,
                                                  u16* __restrict__ Op,
                                                  float* __restrict__ Lp) {
    int h = blockIdx.y;
    int q0 = blockIdx.x * 64;
    int sp = blockIdx.z;
    int tid = threadIdx.x;
    int wid = tid >> 6, lane = tid & 63;
    int lo16 = lane & 15, quad = lane >> 4;

    __shared__ u16 Kt[64 * LDK];
    __shared__ u16 Vt[32 * LDV];
    __shared__ u16 Pt[4][16 * LDV];

    bf16x8 aq = *(const bf16x8*)(Qh + ((size_t)h * NTOK + q0 + wid * 16 + lo16) * 32 + quad * 8);

    floatx4 o0 = {0.f, 0.f, 0.f, 0.f};
    floatx4 o1 = {0.f, 0.f, 0.f, 0.f};
    float l = 0.f;

    int krow = tid >> 2, kseg = tid & 3;
    int vrow = tid >> 3, vseg = tid & 7;
    int kbase = sp * (NTOK / SPLIT);

    for (int kt = 0; kt < NTOK / SPLIT / 64; ++kt) {
        int k0 = kbase + kt * 64;
        uint4 kreg = *(const uint4*)(Kh + ((size_t)h * NTOK + k0 + krow) * 32 + kseg * 8);
        uint4 vreg = *(const uint4*)(Vc + (size_t)(h * 32 + vrow) * NTOK + k0 + vseg * 8);
        __syncthreads();
        *(uint4*)&Kt[krow * LDK + kseg * 8] = kreg;
        *(uint4*)&Vt[vrow * LDV + vseg * 8] = vreg;
        __syncthreads();

        // S^T = K Q^T: row = key (c*16+quad*4+r), col = q (lo16)
        floatx4 s[4];
        floatx4 z = {0.f, 0.f, 0.f, 0.f};
#pragma unroll
        for (int c = 0; c < 4; ++c) {
            bf16x8 ak = *(const bf16x8*)&Kt[(c * 16 + lo16) * LDK + quad * 8];
            s[c] = __builtin_amdgcn_mfma_f32_16x16x32_bf16(ak, aq, z, 0, 0, 0);
        }
        // p = exp2(s) (no max subtraction; scores are O(1)); accumulate l
        float rs = 0.f;
#pragma unroll
        for (int c = 0; c < 4; ++c)
#pragma unroll
            for (int r = 0; r < 4; ++r) {
                float p = __builtin_amdgcn_exp2f(s[c][r]);
                s[c][r] = p;
                rs += p;
            }
        rs += __shfl_xor(rs, 16, 64);
        rs += __shfl_xor(rs, 32, 64);
        l += rs;
        // P -> LDS [q][key] (wave-private, no barrier needed)
#pragma unroll
        for (int c = 0; c < 4; ++c) {
            uint2 w;
            w.x = pkbf(s[c][0], s[c][1]);
            w.y = pkbf(s[c][2], s[c][3]);
            *(uint2*)&Pt[wid][lo16 * LDV + c * 16 + quad * 4] = w;
        }
        // O^T += V P: row = d, col = q
#pragma unroll
        for (int kc = 0; kc < 2; ++kc) {
            bf16x8 bp = *(const bf16x8*)&Pt[wid][lo16 * LDV + kc * 32 + quad * 8];
            bf16x8 av0 = *(const bf16x8*)&Vt[lo16 * LDV + kc * 32 + quad * 8];
            bf16x8 av1 = *(const bf16x8*)&Vt[(16 + lo16) * LDV + kc * 32 + quad * 8];
            o0 = __builtin_amdgcn_mfma_f32_16x16x32_bf16(av0, bp, o0, 0, 0, 0);
            o1 = __builtin_amdgcn_mfma_f32_16x16x32_bf16(av1, bp, o1, 0, 0, 0);
        }
    }

    size_t tok = q0 + wid * 16 + lo16;
    size_t obase = ((size_t)(sp * 8 + h) * NTOK + tok) * 32;
    uint2 w0; w0.x = pkbf(o0[0], o0[1]); w0.y = pkbf(o0[2], o0[3]);
    *(uint2*)(Op + obase + quad * 4) = w0;
    uint2 w1; w1.x = pkbf(o1[0], o1[1]); w1.y = pkbf(o1[2], o1[3]);
    *(uint2*)(Op + obase + 16 + quad * 4) = w1;
    if (lane < 16) Lp[(size_t)(sp * 8 + h) * NTOK + tok] = l;
}

// ---------------- combine split partials -> fused bf16 [tok][256] ----------------
__global__ __launch_bounds__(256) void k_comb(const u16* __restrict__ Op,
                                              const float* __restrict__ Lp,
                                              u16* __restrict__ fused) {
    int n = blockIdx.x * 4 + (threadIdx.x >> 6);
    int lane = threadIdx.x & 63;
    int c = lane * 4;
    int h = c >> 5, d = c & 31;
    float4 o = {0.f, 0.f, 0.f, 0.f};
    float l = 0.f;
#pragma unroll
    for (int s = 0; s < SPLIT; ++s) {
        size_t base = ((size_t)(s * 8 + h) * NTOK + n) * 32 + d;
        uint2 u = *(const uint2*)(Op + base);
        o.x += bf2f((u16)(u.x & 0xffff)); o.y += bf2f((u16)(u.x >> 16));
        o.z += bf2f((u16)(u.y & 0xffff)); o.w += bf2f((u16)(u.y >> 16));
        l += Lp[(size_t)(s * 8 + h) * NTOK + n];
    }
    float inv = 1.0f / l;
    uint2 w;
    w.x = pkbf(o.x * inv, o.y * inv);
    w.y = pkbf(o.z * inv, o.w * inv);
    *(uint2*)(fused + (size_t)n * CDIM + c) = w;
}

// ------------------------------------------------------------------------------
extern "C" void kernel_launch(void* const* d_in, const int* in_sizes, int n_in,
                              void* d_out, int out_size, void* d_ws, size_t ws_size,
                              hipStream_t stream) {
    const float* rgb    = (const float*)d_in[0];
    const float* dpt    = (const float*)d_in[1];
    const float* x_dpt  = (const float*)d_in[2];
    const float* wq     = (const float*)d_in[3];
    const float* bq     = (const float*)d_in[4];
    const float* wk     = (const float*)d_in[5];
    const float* bk     = (const float*)d_in[6];
    const float* wv     = (const float*)d_in[7];
    const float* bv     = (const float*)d_in[8];
    const float* wo     = (const float*)d_in[9];
    const float* bo     = (const float*)d_in[10];
    const float* g_rgb  = (const float*)d_in[11];
    const float* b_rgb  = (const float*)d_in[12];
    const float* g_dpt  = (const float*)d_in[13];
    const float* b_dpt  = (const float*)d_in[14];
    const float* g1     = (const float*)d_in[15];
    const float* b1     = (const float*)d_in[16];
    const float* g2     = (const float*)d_in[17];
    const float* b2     = (const float*)d_in[18];
    const float* w_mlp1 = (const float*)d_in[19];
    const float* b_mlp1 = (const float*)d_in[20];
    const float* w_mlp2 = (const float*)d_in[21];
    const float* b_mlp2 = (const float*)d_in[22];
    const float* w_de1  = (const float*)d_in[23];
    const float* b_de1  = (const float*)d_in[24];
    const float* w_de2  = (const float*)d_in[25];
    const float* b_de2  = (const float*)d_in[26];
    const float* pos    = (const float*)d_in[27];
    const float* scale  = (const float*)d_in[28];
    float* out = (float*)d_out;

    char* base = (char*)d_ws;
    const size_t MB = 1u << 20;
    float* rgbT    = (float*)(base + 0 * MB);    // launch 1 .. wo residual
    float* dptT    = (float*)(base + 4 * MB);    // launch 1 .. LN
    u16*   outT    = (u16*)(base + 4 * MB);      // wo .. ln1
    float* Lp      = (float*)(base + 6 * MB);    // fattn .. comb (512 KB)
    u16*   out_lnT = (u16*)(base + 6 * MB);      // ln1 .. mlp2
    u16*   relu3T  = (u16*)(base + 8 * MB);      // prep .. peGEMM
    u16*   peT     = (u16*)(base + 10 * MB);     // peGEMM .. LN
    u16*   Op      = (u16*)(base + 8 * MB);      // fattn .. comb (8 MB)
    u16*   hT      = (u16*)(base + 8 * MB);      // mlp1 .. mlp2 (8 MB)
    u16*   aqT     = (u16*)(base + 12 * MB);     // LN .. q-proj
    u16*   akvT    = (u16*)(base + 14 * MB);     // LN .. kv-proj
    u16*   Qhm     = (u16*)(base + 16 * MB);     // qkv .. fattn
    u16*   Khm     = (u16*)(base + 18 * MB);
    u16*   out2T   = (u16*)(base + 16 * MB);     // mlp2 .. ln2
    u16*   Vcm     = (u16*)(base + 20 * MB);     // qkv .. fattn
    u16*   fusedT  = (u16*)(base + 22 * MB);     // comb .. wo
    float* lnoutT  = (float*)(base + 20 * MB);   // ln2 .. tr
    u16*   arena   = (u16*)(base + 24 * MB);     // bf16 weights (1.63 MB)

    bool aw = ws_size >= 26 * MB;
    int wf = aw ? 32 : 0;
    const void* Wq  = aw ? (const void*)(arena + 0)      : (const void*)wq;
    const void* Wk  = aw ? (const void*)(arena + 65536)  : (const void*)wk;
    const void* Wv  = aw ? (const void*)(arena + 131072) : (const void*)wv;
    const void* Wo  = aw ? (const void*)(arena + 196608) : (const void*)wo;
    const void* Wd2 = aw ? (const void*)(arena + 262144) : (const void*)w_de2;
    const void* Wm1 = aw ? (const void*)(arena + 327680) : (const void*)w_mlp1;
    const void* Wm2 = aw ? (const void*)(arena + 589824) : (const void*)w_mlp2;

    // 1: input transposes (rgb, dpt) -> token-major f32
    k_tr2<<<dim3(NTOK / 64, CDIM / 64, 2), 256, 0, stream>>>(rgb, rgbT, dpt, dptT, CDIM, NTOK);
    // 2: downsample+conv3x3+relu (+ weight bf16 conversion)
    k_prep<<<aw ? 256 + 832 : 256, 256, 0, stream>>>(x_dpt, w_de1, b_de1, relu3T,
                                                     wq, wk, wv, wo, w_de2, w_mlp1, w_mlp2, arena);
    // 3: pe = 1x1(relu3) -> peT bf16 token-major
    k_bmm<<<dim3(64, 4, 1), 256, 0, stream>>>(relu3T, Wd2, b_de2, peT, wf,
                                              nullptr, nullptr, nullptr, nullptr, 0,
                                              nullptr, nullptr, nullptr, nullptr, 0,
                                              nullptr, nullptr, CDIM, CDIM);
    // 4: both LayerNorms (+pos+pe)
    k_lnT<<<dim3(1024, 2), 256, 0, stream>>>(rgbT, g_rgb, b_rgb, aqT,
                                             dptT, g_dpt, b_dpt, akvT,
                                             peT, pos, 1, 0);
    // 5: QKV in one launch (q scaled+head-major, k head-major, v channel-major)
    k_bmm<<<dim3(64, 4, 3), 256, 0, stream>>>(aqT, Wq, bq, Qhm, wf | 16 | 64,
                                              akvT, Wk, bk, Khm, wf | 64,
                                              akvT, Wv, bv, Vcm, wf | 2,
                                              nullptr, scale, CDIM, CDIM);
    // 6: split-K flash attention
    k_fattn<<<dim3(64, 8, SPLIT), 256, 0, stream>>>(Qhm, Khm, Vcm, Op, Lp);
    // 7: combine partials
    k_comb<<<1024, 256, 0, stream>>>(Op, Lp, fusedT);
    // 8: output projection + residual(rgbT)
    k_bmm<<<dim3(64, 4, 1), 256, 0, stream>>>(fusedT, Wo, bo, outT, wf | 4,
                                              nullptr, nullptr, nullptr, nullptr, 0,
                                              nullptr, nullptr, nullptr, nullptr, 0,
                                              rgbT, nullptr, CDIM, CDIM);
    // 9: LN1
    k_lnT<<<dim3(1024, 1), 256, 0, stream>>>(outT, g1, b1, out_lnT,
                                             nullptr, nullptr, nullptr, nullptr,
                                             nullptr, nullptr, 0, 0);
    // 10: MLP up + GELU
    k_bmm<<<dim3(64, 16, 1), 256, 0, stream>>>(out_lnT, Wm1, b_mlp1, hT, wf | 1,
                                               nullptr, nullptr, nullptr, nullptr, 0,
                                               nullptr, nullptr, nullptr, nullptr, 0,
                                               nullptr, nullptr, MLPD, CDIM);
    // 11: MLP down + residual(out_lnT)
    k_bmm<<<dim3(64, 4, 1), 256, 0, stream>>>(hT, Wm2, b_mlp2, out2T, wf | 8,
                                              nullptr, nullptr, nullptr, nullptr, 0,
                                              nullptr, nullptr, nullptr, nullptr, 0,
                                              out_lnT, nullptr, CDIM, MLPD);
    // 12: LN2 -> f32 token-major
    k_lnT<<<dim3(1024, 1), 256, 0, stream>>>(out2T, g2, b2, lnoutT,
                                             nullptr, nullptr, nullptr, nullptr,
                                             nullptr, nullptr, 0, 1);
    // 13: final transpose -> [C][N]
    k_tr2<<<dim3(CDIM / 64, NTOK / 64, 1), 256, 0, stream>>>(lnoutT, out, nullptr, nullptr, NTOK, CDIM);
}